// Round 7
// baseline (3810.334 us; speedup 1.0000x reference)
//
#include <hip/hip_runtime.h>
#include <math.h>

#define N_BATCH 128
#define L_SEQ   2048
#define HD      128
#define G4      512

typedef __bf16 bf16x8 __attribute__((ext_vector_type(8)));
typedef float  f32x4  __attribute__((ext_vector_type(4)));

__device__ __forceinline__ float sigmoidf_fast(float x) {
    return __builtin_amdgcn_rcpf(1.0f + __expf(-x));
}
__device__ __forceinline__ float tanhf_fast(float x) {
    float a = fabsf(x);
    float t = 1.0f - 2.0f * __builtin_amdgcn_rcpf(1.0f + __expf(2.0f * a));
    return copysignf(t, x);
}
__device__ __forceinline__ void split8(const float* p, bf16x8& h, bf16x8& l) {
    #pragma unroll
    for (int e = 0; e < 8; ++e) {
        float v = p[e];
        __bf16 hb = (__bf16)v;
        h[e] = hb;
        l[e] = (__bf16)(v - (float)hb);
    }
}
// barrier WITHOUT the vmcnt(0) drain __syncthreads would emit: LDS ordering only.
__device__ __forceinline__ void lds_barrier() {
    asm volatile("s_waitcnt lgkmcnt(0)\n\ts_barrier" ::: "memory");
}

// Split Whh and Wih ([3][512][128] fp32) into bf16 hi/lo; bsum = bih+bhh.
__global__ void prep_split(const float* __restrict__ wh0, const float* __restrict__ wh1,
                           const float* __restrict__ wh2,
                           const float* __restrict__ wi0, const float* __restrict__ wi1,
                           const float* __restrict__ wi2,
                           const float* __restrict__ bi0, const float* __restrict__ bi1,
                           const float* __restrict__ bi2,
                           const float* __restrict__ bh0, const float* __restrict__ bh1,
                           const float* __restrict__ bh2,
                           __bf16* __restrict__ whh_hi, __bf16* __restrict__ whh_lo,
                           __bf16* __restrict__ wih_hi, __bf16* __restrict__ wih_lo,
                           float* __restrict__ bsum)
{
    int i = blockIdx.x * 256 + threadIdx.x;    // 0..393215
    if (i < 196608) {
        int l = i >> 16;
        const float* src = (l == 0) ? wh0 : (l == 1) ? wh1 : wh2;
        float v = src[i & 65535];
        __bf16 h = (__bf16)v;
        whh_hi[i] = h; whh_lo[i] = (__bf16)(v - (float)h);
    } else {
        int j = i - 196608;
        int l = j >> 16;
        const float* src = (l == 0) ? wi0 : (l == 1) ? wi1 : wi2;
        float v = src[j & 65535];
        __bf16 h = (__bf16)v;
        wih_hi[j] = h; wih_lo[j] = (__bf16)(v - (float)h);
    }
    if (i < 1536) {
        int l = i >> 9, k = i & 511;
        const float* bi = (l == 0) ? bi0 : (l == 1) ? bi1 : bi2;
        const float* bh = (l == 0) ? bh0 : (l == 1) ? bh1 : bh2;
        bsum[i] = bi[k] + bh[k];
    }
}

// gx layout: [parity*3+layer][t][sblk(8)][gate(512)][sample(16)] floats.
// z layout:  [parity][t*128 + sample][unit] fp32.
// Stage kernel: bx<24 = recurrence (8 blocks/layer x 16 samples, chunk d-2*lr);
// else MFMA gemm producing chunk (d+1-2*lg)'s gx.
__global__ __launch_bounds__(512, 2) void stage_kernel(
        const float* __restrict__ x, const float* __restrict__ w,
        const __bf16* __restrict__ whh_hi, const __bf16* __restrict__ whh_lo,
        const __bf16* __restrict__ wih_hi, const __bf16* __restrict__ wih_lo,
        const float* __restrict__ bsum,
        float* __restrict__ gxbase,
        float* __restrict__ z1, float* __restrict__ z2,
        float* __restrict__ carry,           // [6][128][128]
        int d, int ct, int nchunk)
{
    const int bx = blockIdx.x;
    const int tid = threadIdx.x;
    const int wv = tid >> 6, lane = tid & 63, q = lane >> 4, cc = lane & 15;
    const size_t gxl = (size_t)ct * 65536;
    const size_t zchunk = (size_t)ct * 16384;

    // h in MFMA-A-fragment order: [buf][g=unit>>3][sample][unit&7]
    __shared__ __align__(16) __bf16 hfhi[2][16][16][8];   // 8 KB
    __shared__ __align__(16) __bf16 hflo[2][16][16][8];   // 8 KB

    if (bx < 24) {
        // ---------------- recurrence role ----------------
        const int lr = bx >> 3;
        const int cr = d - 2 * lr;
        if (cr < 0 || cr >= nchunk) return;
        const int sblk = bx & 7, sbase = sblk * 16;
        const int first = (cr == 0);
        const float* __restrict__ gx =
            gxbase + (size_t)((d & 1) * 3 + lr) * gxl + (size_t)sblk * 8192;
        float* zo = (lr == 0) ? z1 + (d & 1) * zchunk
                   : (lr == 1) ? z2 + (d & 1) * zchunk : nullptr;
        const __bf16* __restrict__ whi = whh_hi + (size_t)lr * 65536;
        const __bf16* __restrict__ wlo = whh_lo + (size_t)lr * 65536;
        float* __restrict__ hprev = carry + (size_t)lr * 16384;
        float* __restrict__ cst   = carry + (size_t)(3 + lr) * 16384;

        // B frags: Whh rows ng=(wv+8*ti)*16+cc, k=ks*32+q*8+j  (R4-verified)
        bf16x8 bh[4][4], bl[4][4];
        #pragma unroll
        for (int ti = 0; ti < 4; ++ti) {
            int ng = (wv + 8 * ti) * 16 + cc;
            #pragma unroll
            for (int ks = 0; ks < 4; ++ks) {
                bh[ti][ks] = *(const bf16x8*)(whi + (size_t)ng * HD + ks * 32 + q * 8);
                bl[ti][ks] = *(const bf16x8*)(wlo + (size_t)ng * HD + ks * 32 + q * 8);
            }
        }

        // init h fragment buffer 0 and c state
        for (int i = tid; i < 2048; i += 512) {
            int m = i >> 7, u = i & 127;
            float v = first ? 0.f : hprev[(size_t)(sbase + m) * HD + u];
            __bf16 hb = (__bf16)v;
            hfhi[0][u >> 3][m][u & 7] = hb;
            hflo[0][u >> 3][m][u & 7] = (__bf16)(v - (float)hb);
        }
        const int uu = wv * 16 + cc;
        f32x4 cstate; cstate[0] = cstate[1] = cstate[2] = cstate[3] = 0.f;
        if (!first) {
            #pragma unroll
            for (int r = 0; r < 4; ++r)
                cstate[r] = cst[(size_t)(sbase + 4 * q + r) * HD + uu];
        }
        __syncthreads();

        // per-lane gx offset within a timestep slab (65536 floats)
        const size_t go[4] = {
            (size_t)((wv + 0) * 16 + cc) * 16 + 4 * q,
            (size_t)((wv + 8) * 16 + cc) * 16 + 4 * q,
            (size_t)((wv + 16) * 16 + cc) * 16 + 4 * q,
            (size_t)((wv + 24) * 16 + cc) * 16 + 4 * q };

        // prefetch depth 2: ga = step tc, gb_ = step tc+1
        f32x4 ga[4], gb_[4];
        #pragma unroll
        for (int ti = 0; ti < 4; ++ti) ga[ti] = *(const f32x4*)(gx + go[ti]);
        {
            int t1 = (1 < ct) ? 1 : 0;
            #pragma unroll
            for (int ti = 0; ti < 4; ++ti)
                gb_[ti] = *(const f32x4*)(gx + (size_t)t1 * 65536 + go[ti]);
        }

        float hv[4] = {0.f, 0.f, 0.f, 0.f};

        for (int tc = 0; tc < ct; tc += 2) {
            // ---------- even step: read buf 0, write buf 1, use ga ----------
            {
                bf16x8 ahi[4], alo[4];
                #pragma unroll
                for (int ks = 0; ks < 4; ++ks) {
                    ahi[ks] = *(const bf16x8*)&hfhi[0][ks * 4 + q][cc][0];
                    alo[ks] = *(const bf16x8*)&hflo[0][ks * 4 + q][cc][0];
                }
                f32x4 acc[4];
                #pragma unroll
                for (int ti = 0; ti < 4; ++ti) {
                    f32x4 dd = ga[ti];
                    #pragma unroll
                    for (int ks = 0; ks < 4; ++ks)
                        dd = __builtin_amdgcn_mfma_f32_16x16x32_bf16(ahi[ks], bh[ti][ks], dd, 0, 0, 0);
                    #pragma unroll
                    for (int ks = 0; ks < 4; ++ks)
                        dd = __builtin_amdgcn_mfma_f32_16x16x32_bf16(ahi[ks], bl[ti][ks], dd, 0, 0, 0);
                    #pragma unroll
                    for (int ks = 0; ks < 4; ++ks)
                        dd = __builtin_amdgcn_mfma_f32_16x16x32_bf16(alo[ks], bh[ti][ks], dd, 0, 0, 0);
                    acc[ti] = dd;
                }
                // prefetch ga <- step tc+2 (consumed 2 steps later; barrier no longer drains it)
                {
                    int tn = (tc + 2 < ct) ? tc + 2 : tc;
                    #pragma unroll
                    for (int ti = 0; ti < 4; ++ti)
                        ga[ti] = *(const f32x4*)(gx + (size_t)tn * 65536 + go[ti]);
                }
                #pragma unroll
                for (int r = 0; r < 4; ++r) {
                    float gi = sigmoidf_fast(acc[0][r]);
                    float gf = sigmoidf_fast(acc[1][r]);
                    float gg = tanhf_fast(acc[2][r]);
                    float go_ = sigmoidf_fast(acc[3][r]);
                    float cn = gf * cstate[r] + gi * gg;
                    cstate[r] = cn;
                    hv[r] = go_ * tanhf_fast(cn);
                    __bf16 hb = (__bf16)hv[r];
                    int s = 4 * q + r;
                    hfhi[1][uu >> 3][s][uu & 7] = hb;
                    hflo[1][uu >> 3][s][uu & 7] = (__bf16)(hv[r] - (float)hb);
                    if (lr < 2)
                        zo[((size_t)tc * N_BATCH + sbase + s) * HD + uu] = hv[r];
                }
                lds_barrier();
            }
            // ---------- odd step: read buf 1, write buf 0, use gb_ ----------
            {
                const int t1 = tc + 1;
                bf16x8 ahi[4], alo[4];
                #pragma unroll
                for (int ks = 0; ks < 4; ++ks) {
                    ahi[ks] = *(const bf16x8*)&hfhi[1][ks * 4 + q][cc][0];
                    alo[ks] = *(const bf16x8*)&hflo[1][ks * 4 + q][cc][0];
                }
                f32x4 acc[4];
                #pragma unroll
                for (int ti = 0; ti < 4; ++ti) {
                    f32x4 dd = gb_[ti];
                    #pragma unroll
                    for (int ks = 0; ks < 4; ++ks)
                        dd = __builtin_amdgcn_mfma_f32_16x16x32_bf16(ahi[ks], bh[ti][ks], dd, 0, 0, 0);
                    #pragma unroll
                    for (int ks = 0; ks < 4; ++ks)
                        dd = __builtin_amdgcn_mfma_f32_16x16x32_bf16(ahi[ks], bl[ti][ks], dd, 0, 0, 0);
                    #pragma unroll
                    for (int ks = 0; ks < 4; ++ks)
                        dd = __builtin_amdgcn_mfma_f32_16x16x32_bf16(alo[ks], bh[ti][ks], dd, 0, 0, 0);
                    acc[ti] = dd;
                }
                // prefetch gb_ <- step tc+3
                {
                    int tn = (tc + 3 < ct) ? tc + 3 : tc;
                    #pragma unroll
                    for (int ti = 0; ti < 4; ++ti)
                        gb_[ti] = *(const f32x4*)(gx + (size_t)tn * 65536 + go[ti]);
                }
                #pragma unroll
                for (int r = 0; r < 4; ++r) {
                    float gi = sigmoidf_fast(acc[0][r]);
                    float gf = sigmoidf_fast(acc[1][r]);
                    float gg = tanhf_fast(acc[2][r]);
                    float go_ = sigmoidf_fast(acc[3][r]);
                    float cn = gf * cstate[r] + gi * gg;
                    cstate[r] = cn;
                    hv[r] = go_ * tanhf_fast(cn);
                    __bf16 hb = (__bf16)hv[r];
                    int s = 4 * q + r;
                    hfhi[0][uu >> 3][s][uu & 7] = hb;
                    hflo[0][uu >> 3][s][uu & 7] = (__bf16)(hv[r] - (float)hb);
                    if (lr < 2)
                        zo[((size_t)t1 * N_BATCH + sbase + s) * HD + uu] = hv[r];
                }
                lds_barrier();
            }
        }
        #pragma unroll
        for (int r = 0; r < 4; ++r) {
            cst[(size_t)(sbase + 4 * q + r) * HD + uu] = cstate[r];
            hprev[(size_t)(sbase + 4 * q + r) * HD + uu] = hv[r];
        }
    } else {
        // ---------------- gemm role (produces gx for dispatch d+1) ----------------
        const int g = bx - 24;
        const int perl = 2 * ct;
        const int lg = g / perl;
        const int r0 = g - lg * perl;
        const int cg = d + 1 - 2 * lg;
        if (cg < 0 || cg >= nchunk) return;
        const int tg4 = r0 >> 3;             // timestep group (4 steps)
        const int gb = (r0 >> 1) & 3;        // gate block (128 gates)
        const int nb = r0 & 1;               // sample half (64)

        const float* zsrc = nullptr;
        if (lg > 0) {
            size_t po = (size_t)((d & 1) ^ 1) * zchunk;
            zsrc = ((lg == 1) ? z1 : z2) + po;
        }

        const int mt0 = gb * 8 + (wv & 3) * 2;   // 2 M-tiles (gates)
        const int nt0 = (wv >> 2) * 2;           // 2 N-tiles (samples)

        // A frags: Wih rows (reused over 4 timesteps)
        bf16x8 ah[2][4], al[2][4];
        #pragma unroll
        for (int mm = 0; mm < 2; ++mm) {
            int row = (mt0 + mm) * 16 + cc;
            #pragma unroll
            for (int ks = 0; ks < 4; ++ks) {
                ah[mm][ks] = *(const bf16x8*)(wih_hi + (size_t)lg * 65536 + (size_t)row * HD + ks * 32 + q * 8);
                al[mm][ks] = *(const bf16x8*)(wih_lo + (size_t)lg * 65536 + (size_t)row * HD + ks * 32 + q * 8);
            }
        }

        float* __restrict__ gxo0 = gxbase + (size_t)(((d + 1) & 1) * 3 + lg) * gxl;

        for (int t4 = 0; t4 < 4; ++t4) {
            const int tc = tg4 * 4 + t4;
            // B frags: split fp32 source (x/w for layer 0, z plane otherwise)
            bf16x8 zbh[2][4], zbl[2][4];
            #pragma unroll
            for (int nn = 0; nn < 2; ++nn) {
                int n = nb * 64 + (nt0 + nn) * 16 + cc;
                if (lg == 0) {
                    int tg = cg * ct + tc;
                    #pragma unroll
                    for (int ks = 0; ks < 4; ++ks) {
                        const float* src = (ks < 2 ? x : w)
                            + ((size_t)n * L_SEQ + tg) * 64 + (ks & 1) * 32 + q * 8;
                        split8(src, zbh[nn][ks], zbl[nn][ks]);
                    }
                } else {
                    const float* src0 = zsrc + ((size_t)tc * N_BATCH + n) * HD;
                    #pragma unroll
                    for (int ks = 0; ks < 4; ++ks)
                        split8(src0 + ks * 32 + q * 8, zbh[nn][ks], zbl[nn][ks]);
                }
            }

            f32x4 acc[2][2];
            #pragma unroll
            for (int mm = 0; mm < 2; ++mm)
                #pragma unroll
                for (int nn = 0; nn < 2; ++nn) {
                    f32x4 dd; dd[0] = dd[1] = dd[2] = dd[3] = 0.f;
                    #pragma unroll
                    for (int ks = 0; ks < 4; ++ks)
                        dd = __builtin_amdgcn_mfma_f32_16x16x32_bf16(ah[mm][ks], zbh[nn][ks], dd, 0, 0, 0);
                    #pragma unroll
                    for (int ks = 0; ks < 4; ++ks)
                        dd = __builtin_amdgcn_mfma_f32_16x16x32_bf16(ah[mm][ks], zbl[nn][ks], dd, 0, 0, 0);
                    #pragma unroll
                    for (int ks = 0; ks < 4; ++ks)
                        dd = __builtin_amdgcn_mfma_f32_16x16x32_bf16(al[mm][ks], zbh[nn][ks], dd, 0, 0, 0);
                    acc[mm][nn] = dd;
                }

            float* __restrict__ gxo = gxo0 + (size_t)tc * 65536;
            #pragma unroll
            for (int mm = 0; mm < 2; ++mm) {
                f32x4 bb = *(const f32x4*)(bsum + (size_t)lg * G4 + (mt0 + mm) * 16 + 4 * q);
                #pragma unroll
                for (int nn = 0; nn < 2; ++nn) {
                    int sb = nb * 4 + nt0 + nn;
                    #pragma unroll
                    for (int rr = 0; rr < 4; ++rr) {
                        int grow = (mt0 + mm) * 16 + 4 * q + rr;
                        gxo[(size_t)sb * 8192 + (size_t)grow * 16 + cc] = acc[mm][nn][rr] + bb[rr];
                    }
                }
            }
        }
    }
}

__global__ void final_lin(const float* __restrict__ hlast,
                          const float* __restrict__ Wlin,
                          const float* __restrict__ blin,
                          float* __restrict__ out)
{
    int n = threadIdx.x;  // 128
    const float4* h4 = (const float4*)(hlast + (size_t)n * HD);
    const float4* w4 = (const float4*)Wlin;
    float s = 0.f;
    #pragma unroll
    for (int k4 = 0; k4 < 32; ++k4) {
        float4 h = h4[k4];
        float4 ww = w4[k4];
        s += h.x * ww.x + h.y * ww.y + h.z * ww.z + h.w * ww.w;
    }
    out[n] = s + blin[0];
}

extern "C" void kernel_launch(void* const* d_in, const int* in_sizes, int n_in,
                              void* d_out, int out_size, void* d_ws, size_t ws_size,
                              hipStream_t stream)
{
    const float* x = (const float*)d_in[0];
    const float* w = (const float*)d_in[1];
    const float* Wih[3] = {(const float*)d_in[2], (const float*)d_in[6], (const float*)d_in[10]};
    const float* Whh[3] = {(const float*)d_in[3], (const float*)d_in[7], (const float*)d_in[11]};
    const float* bih[3] = {(const float*)d_in[4], (const float*)d_in[8], (const float*)d_in[12]};
    const float* bhh[3] = {(const float*)d_in[5], (const float*)d_in[9], (const float*)d_in[13]};
    const float* Wlin = (const float*)d_in[14];
    const float* blin = (const float*)d_in[15];
    float* out = (float*)d_out;

    // variable bytes = 1,835,008*ct ; fixed ~2.1 MB
    int ct = 8;
    const int cands[5] = {128, 64, 32, 16, 8};
    for (int i = 0; i < 5; ++i) {
        size_t need = 1835008ull * cands[i] + 2200000ull;
        if (need <= ws_size) { ct = cands[i]; break; }
    }
    const int nchunk = L_SEQ / ct;

    float* gxbase = (float*)d_ws;                       // 6*ct*65536 floats
    float* carry  = gxbase + (size_t)6 * ct * 65536;    // 98304 floats
    float* bsum   = carry + 98304;                      // 1536 floats
    __bf16* whh_hi = (__bf16*)(bsum + 1536);
    __bf16* whh_lo = whh_hi + 196608;
    __bf16* wih_hi = whh_lo + 196608;
    __bf16* wih_lo = wih_hi + 196608;
    float* z1 = (float*)(wih_lo + 196608);              // 2*ct*16384 floats each
    float* z2 = z1 + (size_t)2 * ct * 16384;

    prep_split<<<dim3(1536), dim3(256), 0, stream>>>(
        Whh[0], Whh[1], Whh[2], Wih[0], Wih[1], Wih[2],
        bih[0], bih[1], bih[2], bhh[0], bhh[1], bhh[2],
        whh_hi, whh_lo, wih_hi, wih_lo, bsum);

    const int nblk = 24 + 6 * ct;
    for (int d = -1; d <= nchunk + 3; ++d) {
        stage_kernel<<<dim3(nblk), dim3(512), 0, stream>>>(
            x, w, whh_hi, whh_lo, wih_hi, wih_lo, bsum,
            gxbase, z1, z2, carry, d, ct, nchunk);
    }
    final_lin<<<dim3(1), dim3(128), 0, stream>>>(carry + 2 * 16384, Wlin, blin, out);
}